// Round 1
// baseline (92.355 us; speedup 1.0000x reference)
//
#include <hip/hip_runtime.h>
#include <math.h>

// ---------------- problem constants (from setup_inputs) ----------------
// B=64, n_mel=80, T_mel=1000, N_dec=1000, T_enc=250, n_spk=128, n_aug=10, z=16
constexpr int NMEL  = 64 * 80 * 1000;   // 5,120,000 elems per mel tensor
constexpr int NAL   = 64 * 1000 * 250;  // 16,000,000 alignment elems
constexpr int NGATE = 64 * 1000;        // 64,000
constexpr int NKL   = 64 * 16;          // 1024

// block-role partition
#define NB_MEL   960
#define NB_ALIGN 1024
#define NB_GATE  16
#define BID_KL   (NB_MEL + NB_ALIGN + NB_GATE)
#define BID_CE   (BID_KL + 1)
#define NBLOCKS  (BID_CE + 1)

// ws layout (doubles):
// [0] sum_sq(mel_out)  [1] sum_sq(postnet)  [2] sum_gate_bce  [3] sum_kl_terms
// [4] sum_align*g      [5] sum_spk_ce       [6] sum_aug_ce

__device__ inline float wave_red_sum(float v) {
#pragma unroll
    for (int o = 32; o; o >>= 1) v += __shfl_down(v, o, 64);
    return v;
}

// block (256 threads = 4 waves) reduce + one double atomic
__device__ inline void block_atomic_add(float v, double* dst, float* smem) {
    v = wave_red_sum(v);
    const int lane = threadIdx.x & 63, wid = threadIdx.x >> 6;
    if (lane == 0) smem[wid] = v;
    __syncthreads();
    if (threadIdx.x == 0) {
        float s = smem[0] + smem[1] + smem[2] + smem[3];
        atomicAdd(dst, (double)s);
    }
    __syncthreads();
}

__device__ inline float bce_term(float x, float y) {
    return fmaxf(x, 0.0f) - x * y + log1pf(__expf(-fabsf(x)));
}

__global__ __launch_bounds__(256) void tac2_loss_main(
    const float* __restrict__ mel_out, const float* __restrict__ mel_post,
    const float* __restrict__ gate_out, const float* __restrict__ align,
    const float* __restrict__ r_mu,    const float* __restrict__ r_lv,
    const float* __restrict__ spk_out, const float* __restrict__ aug_out,
    const float* __restrict__ mel_tgt, const float* __restrict__ gate_tgt,
    const float* __restrict__ spk_tgt, const float* __restrict__ aug_tgt,
    double* __restrict__ ws)
{
    __shared__ float smem[4];
    const int bid = blockIdx.x, tid = threadIdx.x;

    if (bid < NB_MEL) {
        // two MSE sums vs shared target, float4 vectorized
        const float4* a = (const float4*)mel_out;
        const float4* p = (const float4*)mel_post;
        const float4* t = (const float4*)mel_tgt;
        float s1 = 0.f, s2 = 0.f;
        for (int i = bid * 256 + tid; i < NMEL / 4; i += NB_MEL * 256) {
            float4 av = a[i], pv = p[i], tv = t[i];
            float d;
            d = av.x - tv.x; s1 = fmaf(d, d, s1);
            d = av.y - tv.y; s1 = fmaf(d, d, s1);
            d = av.z - tv.z; s1 = fmaf(d, d, s1);
            d = av.w - tv.w; s1 = fmaf(d, d, s1);
            d = pv.x - tv.x; s2 = fmaf(d, d, s2);
            d = pv.y - tv.y; s2 = fmaf(d, d, s2);
            d = pv.z - tv.z; s2 = fmaf(d, d, s2);
            d = pv.w - tv.w; s2 = fmaf(d, d, s2);
        }
        block_atomic_add(s1, ws + 0, smem);
        block_atomic_add(s2, ws + 1, smem);
    } else if (bid < NB_MEL + NB_ALIGN) {
        // sum alignment[b,n,t] * (1 - exp(-(n/N - t/T)^2 / 0.4))
        const int b2 = bid - NB_MEL;
        const float4* a = (const float4*)align;
        float s = 0.f;
        for (int i = b2 * 256 + tid; i < NAL / 4; i += NB_ALIGN * 256) {
            float4 v = a[i];
            const int base = i * 4;
            float vv[4] = {v.x, v.y, v.z, v.w};
#pragma unroll
            for (int j = 0; j < 4; ++j) {
                const int idx = base + j;
                const int tt = idx % 250;
                const int nn = (idx / 250) % 1000;
                const float d = nn * (1.0f / 1000.0f) - tt * (1.0f / 250.0f);
                const float w = 1.0f - __expf(-2.5f * d * d);
                s = fmaf(vv[j], w, s);
            }
        }
        block_atomic_add(s, ws + 4, smem);
    } else if (bid < NB_MEL + NB_ALIGN + NB_GATE) {
        // BCE-with-logits sum
        const int b2 = bid - (NB_MEL + NB_ALIGN);
        const float4* x4 = (const float4*)gate_out;
        const float4* y4 = (const float4*)gate_tgt;
        float s = 0.f;
        for (int i = b2 * 256 + tid; i < NGATE / 4; i += NB_GATE * 256) {
            float4 x = x4[i], y = y4[i];
            s += bce_term(x.x, y.x) + bce_term(x.y, y.y) +
                 bce_term(x.z, y.z) + bce_term(x.w, y.w);
        }
        block_atomic_add(s, ws + 2, smem);
    } else if (bid == BID_KL) {
        // sum(1 + lv - mu^2 - exp(lv))
        float s = 0.f;
        for (int i = tid; i < NKL; i += 256) {
            const float mu = r_mu[i], lv = r_lv[i];
            s += 1.0f + lv - mu * mu - __expf(lv);
        }
        block_atomic_add(s, ws + 3, smem);
    } else {
        // cross-entropy: one wave per row; rows strided across 4 waves
        const int lane = tid & 63, wid = tid >> 6;
        float spk_s = 0.f, aug_s = 0.f;
        for (int b = wid; b < 64; b += 4) {
            { // speaker: 128 cols -> 2 per lane
                const float* xo = spk_out + b * 128;
                const float* xt = spk_tgt + b * 128;
                const float x0 = xo[lane], x1 = xo[lane + 64];
                const float t0 = xt[lane], t1 = xt[lane + 64];
                float bv; int bi;
                if (t0 >= t1) { bv = t0; bi = lane; } else { bv = t1; bi = lane + 64; }
#pragma unroll
                for (int o = 32; o; o >>= 1) {
                    const float ov = __shfl_xor(bv, o, 64);
                    const int   oi = __shfl_xor(bi, o, 64);
                    if (ov > bv || (ov == bv && oi < bi)) { bv = ov; bi = oi; }
                }
                float m = fmaxf(x0, x1);
#pragma unroll
                for (int o = 32; o; o >>= 1) m = fmaxf(m, __shfl_xor(m, o, 64));
                float e = __expf(x0 - m) + __expf(x1 - m);
#pragma unroll
                for (int o = 32; o; o >>= 1) e += __shfl_xor(e, o, 64);
                if (lane == 0) spk_s += m + logf(e) - xo[bi];
            }
            { // aug: 10 cols
                const float* ao = aug_out + b * 10;
                const float* at = aug_tgt + b * 10;
                const float x  = (lane < 10) ? ao[lane] : -INFINITY;
                float bv = (lane < 10) ? at[lane] : -INFINITY;
                int   bi = (lane < 10) ? lane : (1 << 30);
#pragma unroll
                for (int o = 32; o; o >>= 1) {
                    const float ov = __shfl_xor(bv, o, 64);
                    const int   oi = __shfl_xor(bi, o, 64);
                    if (ov > bv || (ov == bv && oi < bi)) { bv = ov; bi = oi; }
                }
                float m = x;
#pragma unroll
                for (int o = 32; o; o >>= 1) m = fmaxf(m, __shfl_xor(m, o, 64));
                float e = (lane < 10) ? __expf(x - m) : 0.0f;
#pragma unroll
                for (int o = 32; o; o >>= 1) e += __shfl_xor(e, o, 64);
                if (lane == 0) aug_s += m + logf(e) - ao[bi];
            }
        }
        if (lane == 0) {
            atomicAdd(ws + 5, (double)spk_s);
            atomicAdd(ws + 6, (double)aug_s);
        }
    }
}

__global__ void tac2_loss_final(const double* __restrict__ ws,
                                const int* __restrict__ step_p,
                                float* __restrict__ out)
{
    if (threadIdx.x == 0 && blockIdx.x == 0) {
        const double mel   = ws[0] / (double)NMEL + ws[1] / (double)NMEL;
        const double gate  = ws[2] / (double)NGATE;
        const double kl    = -0.5 * ws[3];
        const double alo   = fabs(ws[4]);
        const double spk   = ws[5] / 64.0;
        const double aug   = ws[6] / 64.0;
        const double step  = (double)step_p[0];
        const double w     = 1.0 / (1.0 + exp(-0.0025 * (step - 10000.0)));
        const double total = 10.0 * (mel + gate) + 0.01 * (kl * w) +
                             0.1 * spk + 0.1 * aug + 0.0005 * alo;
        out[0] = (float)total;
        out[1] = (float)(mel + gate);
        out[2] = (float)kl;
        out[3] = (float)w;
        out[4] = (float)spk;
        out[5] = (float)aug;
        out[6] = (float)alo;
    }
}

extern "C" void kernel_launch(void* const* d_in, const int* in_sizes, int n_in,
                              void* d_out, int out_size, void* d_ws, size_t ws_size,
                              hipStream_t stream) {
    const float* mel_out  = (const float*)d_in[0];
    const float* mel_post = (const float*)d_in[1];
    const float* gate_out = (const float*)d_in[2];
    const float* align    = (const float*)d_in[3];
    const float* r_mu     = (const float*)d_in[4];
    const float* r_lv     = (const float*)d_in[5];
    const float* spk_out  = (const float*)d_in[6];
    const float* aug_out  = (const float*)d_in[7];
    const float* mel_tgt  = (const float*)d_in[8];
    const float* gate_tgt = (const float*)d_in[9];
    const float* spk_tgt  = (const float*)d_in[10];
    const float* aug_tgt  = (const float*)d_in[11];
    const int*   step_p   = (const int*)d_in[12];

    double* ws = (double*)d_ws;
    hipMemsetAsync(d_ws, 0, 7 * sizeof(double), stream);

    tac2_loss_main<<<NBLOCKS, 256, 0, stream>>>(
        mel_out, mel_post, gate_out, align, r_mu, r_lv, spk_out, aug_out,
        mel_tgt, gate_tgt, spk_tgt, aug_tgt, ws);

    tac2_loss_final<<<1, 64, 0, stream>>>(ws, step_p, (float*)d_out);
}

// Round 2
// 61.864 us; speedup vs baseline: 1.4929x; 1.4929x over previous
//
#include <hip/hip_runtime.h>
#include <math.h>

// ---------------- problem constants (from setup_inputs) ----------------
// B=64, n_mel=80, T_mel=1000, N_dec=1000, T_enc=250, n_spk=128, n_aug=10, z=16
constexpr int NMEL  = 64 * 80 * 1000;   // 5,120,000 elems per mel tensor
constexpr int NAL   = 64 * 1000 * 250;  // 16,000,000 alignment elems
constexpr int NGATE = 64 * 1000;        // 64,000
constexpr int NKL   = 64 * 16;          // 1024

// block-role partition
#define NB_MEL   960
#define NB_ALIGN 1024
#define NB_GATE  16
#define BID_KL   (NB_MEL + NB_ALIGN + NB_GATE)
#define BID_CE   (BID_KL + 1)
#define NBLOCKS  (BID_CE + 1)

// ws layout (doubles), one slot per block -> NO atomics, no contention:
// [0    .. 959 ] mel s1 partials (per mel block)
// [1024 .. 1983] mel s2 partials
// [2048 .. 3071] align partials
// [3072 .. 3087] gate partials
// [3088] kl   [3089] spk   [3090] aug
#define WS_MEL1  0
#define WS_MEL2  1024
#define WS_AL    2048
#define WS_GATE  3072
#define WS_KL    3088
#define WS_SPK   3089
#define WS_AUG   3090

__device__ inline float wave_red_sum(float v) {
#pragma unroll
    for (int o = 32; o; o >>= 1) v += __shfl_down(v, o, 64);
    return v;
}

// block (256 threads = 4 waves) reduce; thread 0 stores ONE double (no atomic)
__device__ inline void block_store(float v, double* dst, float* smem) {
    v = wave_red_sum(v);
    const int lane = threadIdx.x & 63, wid = threadIdx.x >> 6;
    if (lane == 0) smem[wid] = v;
    __syncthreads();
    if (threadIdx.x == 0) {
        double s = (double)smem[0] + (double)smem[1] +
                   (double)smem[2] + (double)smem[3];
        *dst = s;
    }
    __syncthreads();
}

__device__ inline float bce_term(float x, float y) {
    return fmaxf(x, 0.0f) - x * y + log1pf(__expf(-fabsf(x)));
}

__global__ __launch_bounds__(256) void tac2_loss_main(
    const float* __restrict__ mel_out, const float* __restrict__ mel_post,
    const float* __restrict__ gate_out, const float* __restrict__ align,
    const float* __restrict__ r_mu,    const float* __restrict__ r_lv,
    const float* __restrict__ spk_out, const float* __restrict__ aug_out,
    const float* __restrict__ mel_tgt, const float* __restrict__ gate_tgt,
    const float* __restrict__ spk_tgt, const float* __restrict__ aug_tgt,
    double* __restrict__ ws)
{
    __shared__ float smem[4];
    const int bid = blockIdx.x, tid = threadIdx.x;

    if (bid < NB_MEL) {
        // two MSE sums vs shared target, float4 vectorized
        const float4* a = (const float4*)mel_out;
        const float4* p = (const float4*)mel_post;
        const float4* t = (const float4*)mel_tgt;
        float s1 = 0.f, s2 = 0.f;
        for (int i = bid * 256 + tid; i < NMEL / 4; i += NB_MEL * 256) {
            float4 av = a[i], pv = p[i], tv = t[i];
            float d;
            d = av.x - tv.x; s1 = fmaf(d, d, s1);
            d = av.y - tv.y; s1 = fmaf(d, d, s1);
            d = av.z - tv.z; s1 = fmaf(d, d, s1);
            d = av.w - tv.w; s1 = fmaf(d, d, s1);
            d = pv.x - tv.x; s2 = fmaf(d, d, s2);
            d = pv.y - tv.y; s2 = fmaf(d, d, s2);
            d = pv.z - tv.z; s2 = fmaf(d, d, s2);
            d = pv.w - tv.w; s2 = fmaf(d, d, s2);
        }
        block_store(s1, ws + WS_MEL1 + bid, smem);
        block_store(s2, ws + WS_MEL2 + bid, smem);
    } else if (bid < NB_MEL + NB_ALIGN) {
        // sum alignment[b,n,t] * (1 - exp(-(n/N - t/T)^2 / 0.4))
        const int b2 = bid - NB_MEL;
        const float4* a = (const float4*)align;
        float s = 0.f;
        for (int i = b2 * 256 + tid; i < NAL / 4; i += NB_ALIGN * 256) {
            float4 v = a[i];
            const int base = i * 4;
            float vv[4] = {v.x, v.y, v.z, v.w};
#pragma unroll
            for (int j = 0; j < 4; ++j) {
                const int idx = base + j;
                const int tt = idx % 250;
                const int nn = (idx / 250) % 1000;
                const float d = nn * (1.0f / 1000.0f) - tt * (1.0f / 250.0f);
                const float w = 1.0f - __expf(-2.5f * d * d);
                s = fmaf(vv[j], w, s);
            }
        }
        block_store(s, ws + WS_AL + b2, smem);
    } else if (bid < NB_MEL + NB_ALIGN + NB_GATE) {
        // BCE-with-logits sum
        const int b2 = bid - (NB_MEL + NB_ALIGN);
        const float4* x4 = (const float4*)gate_out;
        const float4* y4 = (const float4*)gate_tgt;
        float s = 0.f;
        for (int i = b2 * 256 + tid; i < NGATE / 4; i += NB_GATE * 256) {
            float4 x = x4[i], y = y4[i];
            s += bce_term(x.x, y.x) + bce_term(x.y, y.y) +
                 bce_term(x.z, y.z) + bce_term(x.w, y.w);
        }
        block_store(s, ws + WS_GATE + b2, smem);
    } else if (bid == BID_KL) {
        // sum(1 + lv - mu^2 - exp(lv))
        float s = 0.f;
        for (int i = tid; i < NKL; i += 256) {
            const float mu = r_mu[i], lv = r_lv[i];
            s += 1.0f + lv - mu * mu - __expf(lv);
        }
        block_store(s, ws + WS_KL, smem);
    } else {
        // cross-entropy: one wave per row; rows strided across 4 waves
        const int lane = tid & 63, wid = tid >> 6;
        float spk_s = 0.f, aug_s = 0.f;
        for (int b = wid; b < 64; b += 4) {
            { // speaker: 128 cols -> 2 per lane
                const float* xo = spk_out + b * 128;
                const float* xt = spk_tgt + b * 128;
                const float x0 = xo[lane], x1 = xo[lane + 64];
                const float t0 = xt[lane], t1 = xt[lane + 64];
                float bv; int bi;
                if (t0 >= t1) { bv = t0; bi = lane; } else { bv = t1; bi = lane + 64; }
#pragma unroll
                for (int o = 32; o; o >>= 1) {
                    const float ov = __shfl_xor(bv, o, 64);
                    const int   oi = __shfl_xor(bi, o, 64);
                    if (ov > bv || (ov == bv && oi < bi)) { bv = ov; bi = oi; }
                }
                float m = fmaxf(x0, x1);
#pragma unroll
                for (int o = 32; o; o >>= 1) m = fmaxf(m, __shfl_xor(m, o, 64));
                float e = __expf(x0 - m) + __expf(x1 - m);
#pragma unroll
                for (int o = 32; o; o >>= 1) e += __shfl_xor(e, o, 64);
                if (lane == 0) spk_s += m + logf(e) - xo[bi];
            }
            { // aug: 10 cols
                const float* ao = aug_out + b * 10;
                const float* at = aug_tgt + b * 10;
                const float x  = (lane < 10) ? ao[lane] : -INFINITY;
                float bv = (lane < 10) ? at[lane] : -INFINITY;
                int   bi = (lane < 10) ? lane : (1 << 30);
#pragma unroll
                for (int o = 32; o; o >>= 1) {
                    const float ov = __shfl_xor(bv, o, 64);
                    const int   oi = __shfl_xor(bi, o, 64);
                    if (ov > bv || (ov == bv && oi < bi)) { bv = ov; bi = oi; }
                }
                float m = x;
#pragma unroll
                for (int o = 32; o; o >>= 1) m = fmaxf(m, __shfl_xor(m, o, 64));
                float e = (lane < 10) ? __expf(x - m) : 0.0f;
#pragma unroll
                for (int o = 32; o; o >>= 1) e += __shfl_xor(e, o, 64);
                if (lane == 0) aug_s += m + logf(e) - ao[bi];
            }
        }
        // wave-uniform per-wave partials -> combine via smem (4 waves)
        __shared__ double ce_sm[4][2];
        if (lane == 0) { ce_sm[wid][0] = (double)spk_s; ce_sm[wid][1] = (double)aug_s; }
        __syncthreads();
        if (tid == 0) {
            ws[WS_SPK] = ce_sm[0][0] + ce_sm[1][0] + ce_sm[2][0] + ce_sm[3][0];
            ws[WS_AUG] = ce_sm[0][1] + ce_sm[1][1] + ce_sm[2][1] + ce_sm[3][1];
        }
    }
}

// reduce one double array of length n with the whole block, fixed order
__device__ inline double block_red_d(const double* __restrict__ p, int n,
                                     double* sd) {
    const int tid = threadIdx.x;
    double s = 0.0;
    for (int i = tid; i < n; i += 256) s += p[i];
#pragma unroll
    for (int o = 32; o; o >>= 1) s += __shfl_down(s, o, 64);
    const int lane = tid & 63, wid = tid >> 6;
    if (lane == 0) sd[wid] = s;
    __syncthreads();
    double r = sd[0] + sd[1] + sd[2] + sd[3];
    __syncthreads();
    return r;
}

__global__ __launch_bounds__(256) void tac2_loss_final(
    const double* __restrict__ ws, const int* __restrict__ step_p,
    float* __restrict__ out)
{
    __shared__ double sd[4];
    const double s_mel1 = block_red_d(ws + WS_MEL1, NB_MEL, sd);
    const double s_mel2 = block_red_d(ws + WS_MEL2, NB_MEL, sd);
    const double s_al   = block_red_d(ws + WS_AL, NB_ALIGN, sd);
    const double s_gate = block_red_d(ws + WS_GATE, NB_GATE, sd);

    if (threadIdx.x == 0) {
        const double mel   = s_mel1 / (double)NMEL + s_mel2 / (double)NMEL;
        const double gate  = s_gate / (double)NGATE;
        const double kl    = -0.5 * ws[WS_KL];
        const double alo   = fabs(s_al);
        const double spk   = ws[WS_SPK] / 64.0;
        const double aug   = ws[WS_AUG] / 64.0;
        const double step  = (double)step_p[0];
        const double w     = 1.0 / (1.0 + exp(-0.0025 * (step - 10000.0)));
        const double total = 10.0 * (mel + gate) + 0.01 * (kl * w) +
                             0.1 * spk + 0.1 * aug + 0.0005 * alo;
        out[0] = (float)total;
        out[1] = (float)(mel + gate);
        out[2] = (float)kl;
        out[3] = (float)w;
        out[4] = (float)spk;
        out[5] = (float)aug;
        out[6] = (float)alo;
    }
}

extern "C" void kernel_launch(void* const* d_in, const int* in_sizes, int n_in,
                              void* d_out, int out_size, void* d_ws, size_t ws_size,
                              hipStream_t stream) {
    const float* mel_out  = (const float*)d_in[0];
    const float* mel_post = (const float*)d_in[1];
    const float* gate_out = (const float*)d_in[2];
    const float* align    = (const float*)d_in[3];
    const float* r_mu     = (const float*)d_in[4];
    const float* r_lv     = (const float*)d_in[5];
    const float* spk_out  = (const float*)d_in[6];
    const float* aug_out  = (const float*)d_in[7];
    const float* mel_tgt  = (const float*)d_in[8];
    const float* gate_tgt = (const float*)d_in[9];
    const float* spk_tgt  = (const float*)d_in[10];
    const float* aug_tgt  = (const float*)d_in[11];
    const int*   step_p   = (const int*)d_in[12];

    double* ws = (double*)d_ws;

    tac2_loss_main<<<NBLOCKS, 256, 0, stream>>>(
        mel_out, mel_post, gate_out, align, r_mu, r_lv, spk_out, aug_out,
        mel_tgt, gate_tgt, spk_tgt, aug_tgt, ws);

    tac2_loss_final<<<1, 256, 0, stream>>>(ws, step_p, (float*)d_out);
}